// Round 1
// baseline (1748.410 us; speedup 1.0000x reference)
//
#include <hip/hip_runtime.h>

#define DEV __device__ __forceinline__

typedef __bf16 bf16x8 __attribute__((ext_vector_type(8)));
typedef unsigned short ushort8v __attribute__((ext_vector_type(8)));
typedef float floatx4 __attribute__((ext_vector_type(4)));

DEV unsigned short f2bf(float f) {
  unsigned int u = __float_as_uint(f);
  u += 0x7fffu + ((u >> 16) & 1u);   // RNE
  return (unsigned short)(u >> 16);
}

// ---------------- cast fp32 -> bf16 (vectorized) ----------------
__global__ __launch_bounds__(256) void cast_bf16_kernel(
    const float* __restrict__ in, unsigned short* __restrict__ out, int n4) {
  int i = blockIdx.x * 256 + threadIdx.x;
  if (i >= n4) return;
  float4 v = ((const float4*)in)[i];
  ushort4 o;
  o.x = f2bf(v.x); o.y = f2bf(v.y); o.z = f2bf(v.z); o.w = f2bf(v.w);
  ((ushort4*)out)[i] = o;
}

// ---------------- tiled transpose + cast: out[C][R] = bf16(in[R][C]) ----------------
__global__ __launch_bounds__(256) void transpose_cast_kernel(
    const float* __restrict__ in, unsigned short* __restrict__ out, int R, int C) {
  __shared__ float tile[32][33];
  int c0 = blockIdx.x * 32, r0 = blockIdx.y * 32;
  int tx = threadIdx.x, ty = threadIdx.y;
#pragma unroll
  for (int j = 0; j < 32; j += 8)
    tile[ty + j][tx] = in[(long)(r0 + ty + j) * C + (c0 + tx)];
  __syncthreads();
#pragma unroll
  for (int j = 0; j < 32; j += 8)
    out[(long)(c0 + ty + j) * R + (r0 + tx)] = f2bf(tile[tx][ty + j]);
}

// ---------------- generic NT GEMM: C[M,N] = A[M,K] * B[N,K]^T, bf16 MFMA ----------------
// Per-wave 64x64 (4x4 tiles of 16x16x32), block = WM x WN waves.
enum GemmMode { M_QPROJ = 0, M_KPROJ, M_VPROJ, M_SCORES, M_CTX, M_OPROJ, M_FFN1, M_FFN2 };

template <int MODE, int WM, int WN>
__global__ __launch_bounds__(WM * WN * 64)
void gemm_nt(const void* __restrict__ Ap, const unsigned short* __restrict__ Bp,
             const float* __restrict__ bias, void* __restrict__ Cp,
             const float* __restrict__ mask, int K, int ldA, int ldB,
             long zsA, long zsB) {
  constexpr int BM = WM * 64, BN = WN * 64, BK = 32, LDK = 40;  // LDK pad: 80B rows, 16B aligned
  constexpr int NT = WM * WN * 64;
  constexpr bool A_F32 = (MODE == M_CTX);
  __shared__ unsigned short As[BM * LDK];
  __shared__ unsigned short Bs[BN * LDK];

  const int tid = threadIdx.x;
  const int z = blockIdx.z;
  const long bm = (long)blockIdx.y * BM;
  const long bn = (long)blockIdx.x * BN;

  const float* Af = nullptr;
  const unsigned short* Ab = nullptr;
  if constexpr (A_F32) Af = (const float*)Ap + (long)z * zsA + bm * ldA;
  else                 Ab = (const unsigned short*)Ap + (long)z * zsA + bm * ldA;
  const unsigned short* B = Bp + (long)z * zsB + bn * ldB;

  const int wave = tid >> 6, lane = tid & 63;
  const int wn = wave % WN, wm = wave / WN;
  const int lr = lane & 15, kq = lane >> 4;  // fragment row/col, k-quad

  floatx4 acc[4][4];
#pragma unroll
  for (int mt = 0; mt < 4; ++mt)
#pragma unroll
    for (int nt = 0; nt < 4; ++nt) acc[mt][nt] = floatx4{0.f, 0.f, 0.f, 0.f};

  for (int k0 = 0; k0 < K; k0 += BK) {
    __syncthreads();
    // stage A tile [BM][BK]
#pragma unroll
    for (int c = tid; c < BM * 4; c += NT) {
      int r = c >> 2, kc = (c & 3) << 3;
      unsigned short* dst = &As[r * LDK + kc];
      if constexpr (A_F32) {
        const float* src = Af + (long)r * ldA + k0 + kc;
        float4 v0 = *(const float4*)src;
        float4 v1 = *(const float4*)(src + 4);
        ushort4 a{f2bf(v0.x), f2bf(v0.y), f2bf(v0.z), f2bf(v0.w)};
        ushort4 b{f2bf(v1.x), f2bf(v1.y), f2bf(v1.z), f2bf(v1.w)};
        *(ushort4*)dst = a;
        *(ushort4*)(dst + 4) = b;
      } else {
        *(ushort8v*)dst = *(const ushort8v*)(Ab + (long)r * ldA + k0 + kc);
      }
    }
    // stage B tile [BN][BK]
#pragma unroll
    for (int c = tid; c < BN * 4; c += NT) {
      int r = c >> 2, kc = (c & 3) << 3;
      *(ushort8v*)&Bs[r * LDK + kc] = *(const ushort8v*)(B + (long)r * ldB + k0 + kc);
    }
    __syncthreads();

    bf16x8 af[4], bfr[4];
#pragma unroll
    for (int mt = 0; mt < 4; ++mt)
      af[mt] = *(const bf16x8*)&As[(wm * 64 + mt * 16 + lr) * LDK + kq * 8];
#pragma unroll
    for (int nt = 0; nt < 4; ++nt)
      bfr[nt] = *(const bf16x8*)&Bs[(wn * 64 + nt * 16 + lr) * LDK + kq * 8];
#pragma unroll
    for (int mt = 0; mt < 4; ++mt)
#pragma unroll
      for (int nt = 0; nt < 4; ++nt)
        acc[mt][nt] = __builtin_amdgcn_mfma_f32_16x16x32_bf16(af[mt], bfr[nt], acc[mt][nt], 0, 0, 0);
  }

  // epilogue: C/D layout col = lane&15 (lr), row = (lane>>4)*4 + i (kq)
#pragma unroll
  for (int mt = 0; mt < 4; ++mt) {
#pragma unroll
    for (int nt = 0; nt < 4; ++nt) {
#pragma unroll
      for (int i = 0; i < 4; ++i) {
        long gm = bm + wm * 64 + mt * 16 + kq * 4 + i;
        long gn = bn + wn * 64 + nt * 16 + lr;
        float v = acc[mt][nt][i];
        if constexpr (MODE == M_QPROJ || MODE == M_KPROJ) {
          v += bias[gn];
          if constexpr (MODE == M_QPROJ) v *= 0.125f;  // fold 1/sqrt(HD)
          long b = gm >> 10, s = gm & 1023, h = gn >> 6, hd = gn & 63;
          ((unsigned short*)Cp)[((b * 16 + h) << 16) + (s << 6) + hd] = f2bf(v);
        } else if constexpr (MODE == M_VPROJ) {
          v += bias[gn];
          long b = gm >> 10, s = gm & 1023, h = gn >> 6, hd = gn & 63;
          ((unsigned short*)Cp)[((b * 16 + h) << 16) + (hd << 10) + s] = f2bf(v);  // V^T layout
        } else if constexpr (MODE == M_SCORES) {
          v += (1.0f - mask[(long)(z >> 4) * 1024 + gn]) * -10000.0f;
          ((float*)Cp)[(long)z * 1048576 + gm * 1024 + gn] = v;
        } else if constexpr (MODE == M_CTX) {
          long b = z >> 4, h = z & 15;
          ((unsigned short*)Cp)[((b * 1024 + gm) << 10) + (h << 6) + gn] = f2bf(v);
        } else if constexpr (MODE == M_OPROJ || MODE == M_FFN2) {
          ((float*)Cp)[gm * 1024 + gn] = v + bias[gn];
        } else if constexpr (MODE == M_FFN1) {
          ((unsigned short*)Cp)[gm * 4096 + gn] = f2bf(fmaxf(v + bias[gn], 0.f));
        }
      }
    }
  }
}

// ---------------- row softmax in place (1024 cols, fp32) ----------------
__global__ __launch_bounds__(256) void softmax_kernel(float* __restrict__ p) {
  long row = blockIdx.x;
  float* x = p + (row << 10);
  int t = threadIdx.x, wid = t >> 6, lane = t & 63;
  float4 v = ((float4*)x)[t];
  float m = fmaxf(fmaxf(v.x, v.y), fmaxf(v.z, v.w));
#pragma unroll
  for (int o = 32; o > 0; o >>= 1) m = fmaxf(m, __shfl_down(m, o));
  __shared__ float sm[4], ss[4];
  if (lane == 0) sm[wid] = m;
  __syncthreads();
  m = fmaxf(fmaxf(sm[0], sm[1]), fmaxf(sm[2], sm[3]));
  v.x = __expf(v.x - m); v.y = __expf(v.y - m);
  v.z = __expf(v.z - m); v.w = __expf(v.w - m);
  float s = v.x + v.y + v.z + v.w;
#pragma unroll
  for (int o = 32; o > 0; o >>= 1) s += __shfl_down(s, o);
  if (lane == 0) ss[wid] = s;
  __syncthreads();
  s = ss[0] + ss[1] + ss[2] + ss[3];
  float r = 1.0f / s;
  v.x *= r; v.y *= r; v.z *= r; v.w *= r;
  ((float4*)x)[t] = v;
}

// ---------------- LayerNorm helpers ----------------
DEV void block_reduce2(float& s, float& s2, float* buf) {
  int wid = threadIdx.x >> 6, lane = threadIdx.x & 63;
#pragma unroll
  for (int o = 32; o > 0; o >>= 1) { s += __shfl_down(s, o); s2 += __shfl_down(s2, o); }
  if (lane == 0) { buf[wid] = s; buf[4 + wid] = s2; }
  __syncthreads();
  s = buf[0] + buf[1] + buf[2] + buf[3];
  s2 = buf[4] + buf[5] + buf[6] + buf[7];
  __syncthreads();
}

// y1 = LN(proj + query; g1,b1,1e-8); y2 = LN(query + y1; g2,b2,1e-6) -> fp32 + bf16
__global__ __launch_bounds__(256)
void ln_mha_kernel(const float* __restrict__ proj, const float* __restrict__ query,
                   const float* __restrict__ g1, const float* __restrict__ b1,
                   const float* __restrict__ g2, const float* __restrict__ b2,
                   float* __restrict__ attn_out, unsigned short* __restrict__ attn_out_bf) {
  __shared__ float buf[8];
  long row = blockIdx.x;
  int t = threadIdx.x;
  float4 a = ((const float4*)(proj + (row << 10)))[t];
  float4 q = ((const float4*)(query + (row << 10)))[t];
  float4 x{a.x + q.x, a.y + q.y, a.z + q.z, a.w + q.w};
  float s = x.x + x.y + x.z + x.w;
  float s2 = x.x * x.x + x.y * x.y + x.z * x.z + x.w * x.w;
  block_reduce2(s, s2, buf);
  float mu = s * (1.f / 1024.f);
  float inv = rsqrtf(fmaxf(s2 * (1.f / 1024.f) - mu * mu, 0.f) + 1e-8f);
  float4 g = ((const float4*)g1)[t], bb = ((const float4*)b1)[t];
  float4 y{(x.x - mu) * inv * g.x + bb.x, (x.y - mu) * inv * g.y + bb.y,
           (x.z - mu) * inv * g.z + bb.z, (x.w - mu) * inv * g.w + bb.w};
  float4 x2{q.x + y.x, q.y + y.y, q.z + y.z, q.w + y.w};
  s = x2.x + x2.y + x2.z + x2.w;
  s2 = x2.x * x2.x + x2.y * x2.y + x2.z * x2.z + x2.w * x2.w;
  block_reduce2(s, s2, buf);
  mu = s * (1.f / 1024.f);
  inv = rsqrtf(fmaxf(s2 * (1.f / 1024.f) - mu * mu, 0.f) + 1e-6f);
  g = ((const float4*)g2)[t]; bb = ((const float4*)b2)[t];
  float4 o{(x2.x - mu) * inv * g.x + bb.x, (x2.y - mu) * inv * g.y + bb.y,
           (x2.z - mu) * inv * g.z + bb.z, (x2.w - mu) * inv * g.w + bb.w};
  ((float4*)(attn_out + (row << 10)))[t] = o;
  ushort4 ob{f2bf(o.x), f2bf(o.y), f2bf(o.z), f2bf(o.w)};
  ((ushort4*)(attn_out_bf + (row << 10)))[t] = ob;
}

// out = LN(ffn + res; g,b,1e-6) -> d_out fp32
__global__ __launch_bounds__(256)
void ln_final_kernel(const float* __restrict__ ffn, const float* __restrict__ res,
                     const float* __restrict__ g1, const float* __restrict__ b1,
                     float* __restrict__ out) {
  __shared__ float buf[8];
  long row = blockIdx.x;
  int t = threadIdx.x;
  float4 a = ((const float4*)(ffn + (row << 10)))[t];
  float4 q = ((const float4*)(res + (row << 10)))[t];
  float4 x{a.x + q.x, a.y + q.y, a.z + q.z, a.w + q.w};
  float s = x.x + x.y + x.z + x.w;
  float s2 = x.x * x.x + x.y * x.y + x.z * x.z + x.w * x.w;
  block_reduce2(s, s2, buf);
  float mu = s * (1.f / 1024.f);
  float inv = rsqrtf(fmaxf(s2 * (1.f / 1024.f) - mu * mu, 0.f) + 1e-6f);
  float4 g = ((const float4*)g1)[t], bb = ((const float4*)b1)[t];
  float4 o{(x.x - mu) * inv * g.x + bb.x, (x.y - mu) * inv * g.y + bb.y,
           (x.z - mu) * inv * g.z + bb.z, (x.w - mu) * inv * g.w + bb.w};
  ((float4*)(out + (row << 10)))[t] = o;
}

extern "C" void kernel_launch(void* const* d_in, const int* in_sizes, int n_in,
                              void* d_out, int out_size, void* d_ws, size_t ws_size,
                              hipStream_t stream) {
  const float* query = (const float*)d_in[0];
  const float* key   = (const float*)d_in[1];
  const float* value = (const float*)d_in[2];
  const float* mask  = (const float*)d_in[3];
  const float* wq = (const float*)d_in[4];  const float* bq = (const float*)d_in[5];
  const float* wk = (const float*)d_in[6];  const float* bk = (const float*)d_in[7];
  const float* wv = (const float*)d_in[8];  const float* bv = (const float*)d_in[9];
  const float* wo = (const float*)d_in[10]; const float* bo = (const float*)d_in[11];
  const float* ln_mha_g = (const float*)d_in[12]; const float* ln_mha_b = (const float*)d_in[13];
  const float* w1 = (const float*)d_in[14]; const float* b1 = (const float*)d_in[15];
  const float* w2 = (const float*)d_in[16]; const float* b2 = (const float*)d_in[17];
  const float* ln_attn_g = (const float*)d_in[18]; const float* ln_attn_b = (const float*)d_in[19];
  const float* ln_ffn_g = (const float*)d_in[20];  const float* ln_ffn_b = (const float*)d_in[21];

  // workspace layout (elements); Hid (64MB) aliases [Xq,Xk,Xv,Qh] which are dead by FFN1
  unsigned short* Xq  = (unsigned short*)d_ws;          // 8192x1024
  unsigned short* Xk  = Xq + 8388608;
  unsigned short* Xv  = Xk + 8388608;
  unsigned short* Qh  = Xv + 8388608;                   // [B*H][S][HD]
  unsigned short* Hid = (unsigned short*)d_ws;          // 8192x4096 (alias)
  unsigned short* Kh  = Qh + 8388608;
  unsigned short* VhT = Kh + 8388608;                   // [B*H][HD][S]
  unsigned short* WqT = VhT + 8388608;                  // [N][K]
  unsigned short* WkT = WqT + 1048576;
  unsigned short* WvT = WkT + 1048576;
  unsigned short* WoT = WvT + 1048576;
  unsigned short* W1T = WoT + 1048576;                  // [4096][1024]
  unsigned short* W2T = W1T + 4194304;                  // [1024][4096]
  unsigned short* Ctx = W2T + 4194304;                  // 8192x1024 bf16
  float* tmp1    = (float*)(Ctx + 8388608);             // 8192x1024 fp32 (o-proj out, reused for ffn out)
  float* AttnOut = tmp1 + 8388608;                      // 8192x1024 fp32
  unsigned short* AttnOutBf = (unsigned short*)(AttnOut + 8388608);

  float* attnF = (float*)d_out + 8388608;               // attn_weights region [B*H][S][S]
  float* outF  = (float*)d_out;

  // 1) casts
  cast_bf16_kernel<<<8192, 256, 0, stream>>>(query, Xq, 2097152);
  cast_bf16_kernel<<<8192, 256, 0, stream>>>(key,   Xk, 2097152);
  cast_bf16_kernel<<<8192, 256, 0, stream>>>(value, Xv, 2097152);
  // 2) weight transposes -> [N][K] bf16
  transpose_cast_kernel<<<dim3(32, 32), dim3(32, 8), 0, stream>>>(wq, WqT, 1024, 1024);
  transpose_cast_kernel<<<dim3(32, 32), dim3(32, 8), 0, stream>>>(wk, WkT, 1024, 1024);
  transpose_cast_kernel<<<dim3(32, 32), dim3(32, 8), 0, stream>>>(wv, WvT, 1024, 1024);
  transpose_cast_kernel<<<dim3(32, 32), dim3(32, 8), 0, stream>>>(wo, WoT, 1024, 1024);
  transpose_cast_kernel<<<dim3(128, 32), dim3(32, 8), 0, stream>>>(w1, W1T, 1024, 4096);
  transpose_cast_kernel<<<dim3(32, 128), dim3(32, 8), 0, stream>>>(w2, W2T, 4096, 1024);
  // 3) QKV projections (head-layout epilogues; Q pre-scaled by 0.125)
  gemm_nt<M_QPROJ, 2, 2><<<dim3(8, 64, 1), 256, 0, stream>>>(Xq, WqT, bq, Qh, nullptr, 1024, 1024, 1024, 0, 0);
  gemm_nt<M_KPROJ, 2, 2><<<dim3(8, 64, 1), 256, 0, stream>>>(Xk, WkT, bk, Kh, nullptr, 1024, 1024, 1024, 0, 0);
  gemm_nt<M_VPROJ, 2, 2><<<dim3(8, 64, 1), 256, 0, stream>>>(Xv, WvT, bv, VhT, nullptr, 1024, 1024, 1024, 0, 0);
  // 4) scores = Q K^T (+mask) -> d_out attn region, fp32
  gemm_nt<M_SCORES, 2, 2><<<dim3(8, 8, 128), 256, 0, stream>>>(Qh, Kh, nullptr, attnF, mask, 64, 64, 64, 65536L, 65536L);
  // 5) softmax in place
  softmax_kernel<<<131072, 256, 0, stream>>>(attnF);
  // 6) context = P V  (A = fp32 probs, converted during staging)
  gemm_nt<M_CTX, 2, 1><<<dim3(1, 8, 128), 128, 0, stream>>>(attnF, VhT, nullptr, Ctx, nullptr, 1024, 1024, 1024, 1048576L, 65536L);
  // 7) output projection
  gemm_nt<M_OPROJ, 2, 2><<<dim3(8, 64, 1), 256, 0, stream>>>(Ctx, WoT, bo, tmp1, nullptr, 1024, 1024, 1024, 0, 0);
  // 8) double LayerNorm (MHA-internal eps 1e-8, encoder eps 1e-6)
  ln_mha_kernel<<<8192, 256, 0, stream>>>(tmp1, query, ln_mha_g, ln_mha_b, ln_attn_g, ln_attn_b, AttnOut, AttnOutBf);
  // 9) FFN
  gemm_nt<M_FFN1, 2, 2><<<dim3(32, 64, 1), 256, 0, stream>>>(AttnOutBf, W1T, b1, Hid, nullptr, 1024, 1024, 1024, 0, 0);
  gemm_nt<M_FFN2, 2, 2><<<dim3(8, 64, 1), 256, 0, stream>>>(Hid, W2T, b2, tmp1, nullptr, 4096, 4096, 4096, 0, 0);
  // 10) final LayerNorm -> d_out
  ln_final_kernel<<<8192, 256, 0, stream>>>(tmp1, AttnOut, ln_ffn_g, ln_ffn_b, outF);
}